// Round 6
// baseline (749.657 us; speedup 1.0000x reference)
//
#include <hip/hip_runtime.h>

// GraphSage 2-layer forward, MI355X (gfx950).
// Inputs: raw[1e6][128], W1[128][256], W2[128][256] (bf16 OR f32 — detected on
// device), nodes1[40960] i32, neigh1[40960][10] i32, nodes2[4096] i32,
// neigh2[4096][10] i32.  out: h2[4096][128] (dtype follows inputs).
//
// R5 post-mortem: sorted READS are 3-5x faster (confirmed), but reading the
// staging back in original order re-randomized the reads (~0.8 TB/s ceiling,
// footprint-independent). R6: invert the permutation with random WRITES
// (fire-and-forget, full-line): gather_scatter reads table in sorted order and
// scatter-writes rows directly to ref-ordered rdist; mean_seq then reads rdist
// fully sequentially (node n's 10 neighbor rows are contiguous).
// Pipeline: detect -> memset hist -> hist_refs -> scan8k -> scatter_refs ->
//           gather_scatter(sorted R, random W) -> mean_seq(seq) ->
//           gemm_combined -> sage_layer(L2).

typedef __attribute__((ext_vector_type(8))) short  short8;   // 8 bf16 = 16 B
typedef __attribute__((ext_vector_type(8))) __bf16 bf16x8;   // MFMA operand type
typedef __attribute__((ext_vector_type(4))) float  f32x4;

#define K_NEIGH 10
#define NB      32          // nodes per block (GEMM kernels)
#define PITCH   264         // shorts per LDS combined row (256 + 8 pad)
#define NBUCKET 8192        // table regions: 1M rows >> 7 = 128 rows = 64 KB

__device__ inline float b2f(short s) {
    union { unsigned int u; float f; } c;
    c.u = ((unsigned int)(unsigned short)s) << 16;
    return c.f;
}
__device__ inline short f2b(float f) {
    union { float f; unsigned int u; } c; c.f = f;
    unsigned int u = c.u;
    return (short)((u + 0x7fffu + ((u >> 16) & 1u)) >> 16);  // RNE
}
__device__ inline unsigned int pack2(float lo, float hi) {
    return (unsigned int)(unsigned short)f2b(lo)
         | ((unsigned int)(unsigned short)f2b(hi) << 16);
}
__device__ inline bf16x8 as_bf16x8(short8 s) {
    union { short8 s; bf16x8 b; } c; c.s = s; return c.b;
}

// f32-vs-bf16 input detection (see R0 notes). 1 wave, ballot.
__global__ void detect_f32(const unsigned short* __restrict__ w, int* __restrict__ flag) {
    const int lane = threadIdx.x;                     // 64 threads, 1 wave
    unsigned int e = ((unsigned int)w[2 * lane] >> 7) & 0xFFu;  // bf16 exp field
    unsigned long long m = __ballot(e >= 132u);                 // |x| >= 32
    if (lane == 0) *flag = (m != 0ull) ? 1 : 0;
}

// ---------------------------------------------------------------------------
// Sort machinery: refs r in [0, B1*11): r < B1 -> self ref (nodes[r]);
// else neighbor ref (neigh_flat[r - B1]). Bucket = row_id >> 7.

__global__ void hist_refs(const int* __restrict__ nodes,
                          const int* __restrict__ neigh,   // flat [B1*10]
                          const int B1, const int total,
                          int* __restrict__ hist)
{
    const int r = blockIdx.x * 256 + threadIdx.x;
    if (r < total) {
        const int id = (r < B1) ? nodes[r] : neigh[r - B1];
        atomicAdd(&hist[id >> 7], 1);
    }
}

// Exclusive scan of 8192 ints, one block of 1024 threads (8 per thread).
__global__ void scan8k(const int* __restrict__ hist, int* __restrict__ cursor)
{
    __shared__ int part[1024];
    const int tid = threadIdx.x;
    int v[8], run[8];
    int s = 0;
#pragma unroll
    for (int i = 0; i < 8; ++i) {
        v[i] = hist[tid * 8 + i];
        run[i] = s;               // local exclusive prefix
        s += v[i];
    }
    part[tid] = s;
    __syncthreads();
    for (int off = 1; off < 1024; off <<= 1) {
        int x = (tid >= off) ? part[tid - off] : 0;
        __syncthreads();
        part[tid] += x;
        __syncthreads();
    }
    const int base = part[tid] - s;   // exclusive block prefix
#pragma unroll
    for (int i = 0; i < 8; ++i)
        cursor[tid * 8 + i] = base + run[i];
}

// Emit, for each sorted position p: the row id (sorted_id[p]) and the original
// ref index (ref_of[p]) — the inverse permutation used by the scatter phase.
__global__ void scatter_refs(const int* __restrict__ nodes,
                             const int* __restrict__ neigh,   // flat
                             const int B1, const int total,
                             int* __restrict__ cursor,
                             int* __restrict__ sorted_id,
                             int* __restrict__ ref_of)
{
    const int r = blockIdx.x * 256 + threadIdx.x;
    if (r < total) {
        const int id = (r < B1) ? nodes[r] : neigh[r - B1];
        const int p  = atomicAdd(&cursor[id >> 7], 1);
        sorted_id[p] = id;
        ref_of[p]    = r;
    }
}

// Read table rows in SORTED order (semi-sequential: fast, confirmed R5) and
// scatter-write each row to its ref-ordered slot rdist[ref_of[p]] (random
// full-line writes: fire-and-forget). One wave per 4 sorted positions.
__launch_bounds__(256, 8)
__global__ void gather_scatter(const void* __restrict__ table,
                               const int*  __restrict__ sorted_id,
                               const int*  __restrict__ ref_of,
                               void*       __restrict__ rdist,
                               const int*  __restrict__ flag,
                               const int total, const int table_by_flag)
{
    const int  t    = threadIdx.x;
    const int  lane = t & 63;
    const long p0   = ((long)blockIdx.x * 4 + (t >> 6)) * 4;   // 4 rows/wave
    const bool t32  = table_by_flag && *flag;

    int id[4], rr[4];
#pragma unroll
    for (int j = 0; j < 4; ++j) {
        const long p = p0 + j;
        id[j] = (p < total) ? sorted_id[p] : 0;
        rr[j] = (p < total) ? ref_of[p]    : 0;
    }
    if (t32) {
        const float2* src = (const float2*)table;   // 64 float2 per 512 B row
        float2*       dst = (float2*)rdist;
        float2 v[4];
#pragma unroll
        for (int j = 0; j < 4; ++j) v[j] = src[(long)id[j] * 64 + lane];
#pragma unroll
        for (int j = 0; j < 4; ++j) {
            const long p = p0 + j;
            if (p < total) dst[(long)rr[j] * 64 + lane] = v[j];
        }
    } else {
        const unsigned int* src = (const unsigned int*)table;  // 64 u32 per 256 B row
        unsigned int*       dst = (unsigned int*)rdist;
        unsigned int v[4];
#pragma unroll
        for (int j = 0; j < 4; ++j) v[j] = src[(long)id[j] * 64 + lane];
#pragma unroll
        for (int j = 0; j < 4; ++j) {
            const long p = p0 + j;
            if (p < total) dst[(long)rr[j] * 64 + lane] = v[j];
        }
    }
}

// Mean from ref-ordered rdist: node n's self row at rdist[n]; its 10 neighbor
// rows at rdist[B1 + 10n .. B1 + 10n + 9] — CONTIGUOUS. Fully streaming.
__launch_bounds__(256, 8)
__global__ void mean_seq(const void* __restrict__ rdist,
                         short*      __restrict__ comb,     // [B1][256] bf16
                         const int*  __restrict__ flag,
                         const int B1, const int table_by_flag)
{
    const int t    = threadIdx.x;
    const int lane = t & 63;
    const int n    = blockIdx.x * 4 + (t >> 6);      // wave-uniform
    if (n >= B1) return;
    const bool t32 = table_by_flag && *flag;

    unsigned int sp;
    float a0 = 0.f, a1 = 0.f;
    if (t32) {
        const float2* g = (const float2*)rdist;
        float2 self = g[(long)n * 64 + lane];
        float2 v[K_NEIGH];
#pragma unroll
        for (int k = 0; k < K_NEIGH; ++k)
            v[k] = g[(long)(B1 + n * K_NEIGH + k) * 64 + lane];
#pragma unroll
        for (int k = 0; k < K_NEIGH; ++k) { a0 += v[k].x; a1 += v[k].y; }
        sp = pack2(self.x, self.y);
    } else {
        const unsigned int* g = (const unsigned int*)rdist;
        sp = g[(long)n * 64 + lane];
        unsigned int v[K_NEIGH];
#pragma unroll
        for (int k = 0; k < K_NEIGH; ++k)
            v[k] = g[(long)(B1 + n * K_NEIGH + k) * 64 + lane];
#pragma unroll
        for (int k = 0; k < K_NEIGH; ++k) {
            a0 += b2f((short)(v[k] & 0xFFFFu));
            a1 += b2f((short)(v[k] >> 16));
        }
    }
    const unsigned int gp = pack2(a0 * 0.1f, a1 * 0.1f);
    unsigned int* crow = (unsigned int*)(comb + (long)n * 256);
    crow[lane]      = sp;   // self -> cols [0,128)
    crow[64 + lane] = gp;   // agg  -> cols [128,256)
}

// ---------------------------------------------------------------------------
// Fallback direct gather (R3): used only if ws too small for staging.
__launch_bounds__(256, 8)
__global__ void gather_agg(const void* __restrict__ table,
                           const int*  __restrict__ nodes,
                           const int*  __restrict__ neigh,   // [nn][10]
                           short*      __restrict__ comb,    // [nn][256] bf16
                           const int*  __restrict__ flag,
                           const int table_by_flag)
{
    const int t    = threadIdx.x;
    const int lane = t & 63;
    const int node = blockIdx.x * 4 + (t >> 6);
    const bool t32 = table_by_flag && *flag;

    const int self_id = nodes[node];
    int nid[K_NEIGH];
#pragma unroll
    for (int k = 0; k < K_NEIGH; ++k) nid[k] = neigh[node * K_NEIGH + k];

    unsigned int sp;
    float a0 = 0.f, a1 = 0.f;
    if (t32) {
        const float* base = (const float*)table;
        float2 self = *(const float2*)(base + (long)self_id * 128 + lane * 2);
        float2 v[K_NEIGH];
#pragma unroll
        for (int k = 0; k < K_NEIGH; ++k)
            v[k] = *(const float2*)(base + (long)nid[k] * 128 + lane * 2);
#pragma unroll
        for (int k = 0; k < K_NEIGH; ++k) { a0 += v[k].x; a1 += v[k].y; }
        sp = pack2(self.x, self.y);
    } else {
        const short* base = (const short*)table;
        sp = *(const unsigned int*)(base + (long)self_id * 128 + lane * 2);
        unsigned int v[K_NEIGH];
#pragma unroll
        for (int k = 0; k < K_NEIGH; ++k)
            v[k] = *(const unsigned int*)(base + (long)nid[k] * 128 + lane * 2);
#pragma unroll
        for (int k = 0; k < K_NEIGH; ++k) {
            a0 += b2f((short)(v[k] & 0xFFFFu));
            a1 += b2f((short)(v[k] >> 16));
        }
    }
    unsigned int gp = pack2(a0 * 0.1f, a1 * 0.1f);
    unsigned int* crow = (unsigned int*)(comb + (long)node * 256);
    crow[lane]      = sp;
    crow[64 + lane] = gp;
}

// ---------------------------------------------------------------------------
// GEMM over pre-combined rows: out[i][o] = relu(sum_j comb[i][j] * W[o][j]).
__launch_bounds__(256, 2)
__global__ void gemm_combined(const short* __restrict__ comb,   // [nn][256] bf16
                              const void* __restrict__ Wv,      // [128][256]
                              void*       __restrict__ outv,    // [nn][128]
                              const int*  __restrict__ flag,
                              const int out_by_flag)
{
    __shared__ __align__(16) short lds[NB * PITCH];
    const int t    = threadIdx.x;
    const int blk  = blockIdx.x;
    const int lane = t & 63;
    const int wave = t >> 6;          // wave w owns out cols [32w, 32w+32)
    const int n15  = lane & 15;
    const int q    = lane >> 4;
    const int f32in = *flag;
    const bool o32 = out_by_flag && f32in;

    short8 bfrag[2][8];
    if (!f32in) {
        const short* W = (const short*)Wv;
#pragma unroll
        for (int ot = 0; ot < 2; ++ot) {
            const int o = wave * 32 + ot * 16 + n15;
#pragma unroll
            for (int fk = 0; fk < 8; ++fk)
                bfrag[ot][fk] = *(const short8*)(W + o * 256 + fk * 32 + q * 8);
        }
    } else {
        const float* W = (const float*)Wv;
#pragma unroll
        for (int ot = 0; ot < 2; ++ot) {
            const int o = wave * 32 + ot * 16 + n15;
#pragma unroll
            for (int fk = 0; fk < 8; ++fk) {
                const float* p = W + o * 256 + fk * 32 + q * 8;
                f32x4 v0 = *(const f32x4*)p;
                f32x4 v1 = *(const f32x4*)(p + 4);
                short8 s;
#pragma unroll
                for (int i = 0; i < 4; ++i) { s[i] = f2b(v0[i]); s[4 + i] = f2b(v1[i]); }
                bfrag[ot][fk] = s;
            }
        }
    }

    {
        const int m   = t >> 3;              // row 0..31
        const int col = (t & 7) * 32;        // shorts
        const short* src = comb + (long)blk * (NB * 256) + m * 256 + col;
        short8 x0 = *(const short8*)(src);
        short8 x1 = *(const short8*)(src + 8);
        short8 x2 = *(const short8*)(src + 16);
        short8 x3 = *(const short8*)(src + 24);
        short* dst = lds + m * PITCH + col;
        *(short8*)(dst)      = x0;
        *(short8*)(dst + 8)  = x1;
        *(short8*)(dst + 16) = x2;
        *(short8*)(dst + 24) = x3;
    }
    __syncthreads();

    f32x4 acc[2][2] = {};
#pragma unroll
    for (int mb = 0; mb < 2; ++mb) {
        const short* arow = lds + (mb * 16 + n15) * PITCH + q * 8;
        short8 af[8];
#pragma unroll
        for (int fk = 0; fk < 8; ++fk) af[fk] = *(const short8*)(arow + fk * 32);
#pragma unroll
        for (int ot = 0; ot < 2; ++ot)
#pragma unroll
            for (int fk = 0; fk < 8; ++fk)
                acc[mb][ot] = __builtin_amdgcn_mfma_f32_16x16x32_bf16(
                    as_bf16x8(af[fk]), as_bf16x8(bfrag[ot][fk]), acc[mb][ot], 0, 0, 0);
    }

#pragma unroll
    for (int mb = 0; mb < 2; ++mb)
#pragma unroll
        for (int ot = 0; ot < 2; ++ot) {
            const int col = wave * 32 + ot * 16 + n15;
#pragma unroll
            for (int r = 0; r < 4; ++r) {
                const long row = blk * NB + mb * 16 + q * 4 + r;
                float v = acc[mb][ot][r];
                v = v > 0.f ? v : 0.f;
                if (!o32) ((short*)outv)[row * 128 + col] = f2b(v);
                else      ((float*)outv)[row * 128 + col] = v;
            }
        }
}

// ---------------------------------------------------------------------------
// Fused gather+GEMM (layer 2: h1 table is small and cache-resident).
__launch_bounds__(256, 2)
__global__ void sage_layer(const void* __restrict__ table,
                           const void* __restrict__ Wv,       // [128][256] row-major
                           const int*  __restrict__ nodes,
                           const int*  __restrict__ neigh,    // [nn][10]
                           void*       __restrict__ outv,     // [nn][128]
                           const int*  __restrict__ flag,
                           const int table_by_flag, const int out_by_flag)
{
    __shared__ __align__(16) short lds[NB * PITCH];
    const int t    = threadIdx.x;
    const int blk  = blockIdx.x;
    const int lane = t & 63;
    const int wave = t >> 6;
    const int n15  = lane & 15;
    const int q    = lane >> 4;
    const int f32in = *flag;
    const bool t32 = table_by_flag && f32in;
    const bool o32 = out_by_flag && f32in;

    short8 bfrag[2][8];
    if (!f32in) {
        const short* W = (const short*)Wv;
#pragma unroll
        for (int ot = 0; ot < 2; ++ot) {
            const int o = wave * 32 + ot * 16 + n15;
#pragma unroll
            for (int fk = 0; fk < 8; ++fk)
                bfrag[ot][fk] = *(const short8*)(W + o * 256 + fk * 32 + q * 8);
        }
    } else {
        const float* W = (const float*)Wv;
#pragma unroll
        for (int ot = 0; ot < 2; ++ot) {
            const int o = wave * 32 + ot * 16 + n15;
#pragma unroll
            for (int fk = 0; fk < 8; ++fk) {
                const float* p = W + o * 256 + fk * 32 + q * 8;
                f32x4 v0 = *(const f32x4*)p;
                f32x4 v1 = *(const f32x4*)(p + 4);
                short8 s;
#pragma unroll
                for (int i = 0; i < 4; ++i) { s[i] = f2b(v0[i]); s[4 + i] = f2b(v1[i]); }
                bfrag[ot][fk] = s;
            }
        }
    }

    {
        const int m    = t >> 3;
        const int part = t & 7;
        const int gi   = blk * NB + m;
        const int self_id = nodes[gi];
        int nidv[K_NEIGH];
#pragma unroll
        for (int k = 0; k < K_NEIGH; ++k) nidv[k] = neigh[gi * K_NEIGH + k];
        short8 s0, s1;
        float a[16];
#pragma unroll
        for (int i = 0; i < 16; ++i) a[i] = 0.f;

        if (!t32) {
            const short* srow = (const short*)table + (long)self_id * 128 + part * 16;
            s0 = *(const short8*)(srow);
            s1 = *(const short8*)(srow + 8);
#pragma unroll
            for (int k = 0; k < K_NEIGH; ++k) {
                const short* nrow = (const short*)table + (long)nidv[k] * 128 + part * 16;
                short8 v0 = *(const short8*)(nrow);
                short8 v1 = *(const short8*)(nrow + 8);
#pragma unroll
                for (int i = 0; i < 8; ++i) { a[i] += b2f(v0[i]); a[8 + i] += b2f(v1[i]); }
            }
        } else {
            const float* srow = (const float*)table + (long)self_id * 128 + part * 16;
            f32x4 u0 = *(const f32x4*)(srow);
            f32x4 u1 = *(const f32x4*)(srow + 4);
            f32x4 u2 = *(const f32x4*)(srow + 8);
            f32x4 u3 = *(const f32x4*)(srow + 12);
#pragma unroll
            for (int i = 0; i < 4; ++i) {
                s0[i] = f2b(u0[i]); s0[4 + i] = f2b(u1[i]);
                s1[i] = f2b(u2[i]); s1[4 + i] = f2b(u3[i]);
            }
#pragma unroll
            for (int k = 0; k < K_NEIGH; ++k) {
                const float* nrow = (const float*)table + (long)nidv[k] * 128 + part * 16;
                f32x4 v0 = *(const f32x4*)(nrow);
                f32x4 v1 = *(const f32x4*)(nrow + 4);
                f32x4 v2 = *(const f32x4*)(nrow + 8);
                f32x4 v3 = *(const f32x4*)(nrow + 12);
#pragma unroll
                for (int i = 0; i < 4; ++i) {
                    a[i] += v0[i]; a[4 + i] += v1[i]; a[8 + i] += v2[i]; a[12 + i] += v3[i];
                }
            }
        }
        short8 g0, g1;
#pragma unroll
        for (int i = 0; i < 8; ++i) { g0[i] = f2b(a[i] * 0.1f); g1[i] = f2b(a[8 + i] * 0.1f); }
        short* dst = lds + m * PITCH + part * 16;
        *(short8*)(dst)       = s0;
        *(short8*)(dst + 8)   = s1;
        *(short8*)(dst + 128) = g0;
        *(short8*)(dst + 136) = g1;
    }
    __syncthreads();

    f32x4 acc[2][2] = {};
#pragma unroll
    for (int mb = 0; mb < 2; ++mb) {
        const short* arow = lds + (mb * 16 + n15) * PITCH + q * 8;
        short8 af[8];
#pragma unroll
        for (int fk = 0; fk < 8; ++fk) af[fk] = *(const short8*)(arow + fk * 32);
#pragma unroll
        for (int ot = 0; ot < 2; ++ot)
#pragma unroll
            for (int fk = 0; fk < 8; ++fk)
                acc[mb][ot] = __builtin_amdgcn_mfma_f32_16x16x32_bf16(
                    as_bf16x8(af[fk]), as_bf16x8(bfrag[ot][fk]), acc[mb][ot], 0, 0, 0);
    }

#pragma unroll
    for (int mb = 0; mb < 2; ++mb)
#pragma unroll
        for (int ot = 0; ot < 2; ++ot) {
            const int col = wave * 32 + ot * 16 + n15;
#pragma unroll
            for (int r = 0; r < 4; ++r) {
                const long row = blk * NB + mb * 16 + q * 4 + r;
                float v = acc[mb][ot][r];
                v = v > 0.f ? v : 0.f;
                if (!o32) ((short*)outv)[row * 128 + col] = f2b(v);
                else      ((float*)outv)[row * 128 + col] = v;
            }
        }
}

extern "C" void kernel_launch(void* const* d_in, const int* in_sizes, int n_in,
                              void* d_out, int out_size, void* d_ws, size_t ws_size,
                              hipStream_t stream) {
    const void* raw    = d_in[0];
    const void* W1     = d_in[1];
    const void* W2     = d_in[2];
    const int*  nodes1 = (const int*)d_in[3];
    const int*  neigh1 = (const int*)d_in[4];
    const int*  nodes2 = (const int*)d_in[5];
    const int*  neigh2 = (const int*)d_in[6];

    const int B1    = in_sizes[3];                 // 40960
    const int B2    = in_sizes[5];                 // 4096
    const int total = B1 * (1 + K_NEIGH);          // 450560 refs

    // ws layout
    char* ws = (char*)d_ws;
    int*   flag      = (int*)ws;
    size_t o_h1      = 256;
    size_t o_comb    = o_h1   + (size_t)B1 * 128 * 2;     // h1: bf16
    size_t o_hist    = o_comb + (size_t)B1 * 256 * 2;     // comb: bf16
    size_t o_cursor  = o_hist   + (size_t)NBUCKET * 4;
    size_t o_sid     = o_cursor + (size_t)NBUCKET * 4;
    size_t o_ref     = o_sid    + (size_t)total * 4;
    size_t o_rdist   = o_ref    + (size_t)total * 4;
    size_t need      = o_rdist  + (size_t)total * 512;    // f32 ref-ordered rows

    short* h1        = (short*)(ws + o_h1);
    short* comb      = (short*)(ws + o_comb);
    int*   hist      = (int*)(ws + o_hist);
    int*   cursor    = (int*)(ws + o_cursor);
    int*   sorted_id = (int*)(ws + o_sid);
    int*   ref_of    = (int*)(ws + o_ref);
    void*  rdist     = (void*)(ws + o_rdist);

    detect_f32<<<1, 64, 0, stream>>>((const unsigned short*)W1, flag);

    if (ws_size >= need) {
        // Sorted read -> scatter write -> sequential mean.
        hipMemsetAsync(hist, 0, NBUCKET * 4, stream);
        const int gb = (total + 255) / 256;
        hist_refs<<<gb, 256, 0, stream>>>(nodes1, neigh1, B1, total, hist);
        scan8k<<<1, 1024, 0, stream>>>(hist, cursor);
        scatter_refs<<<gb, 256, 0, stream>>>(nodes1, neigh1, B1, total,
                                             cursor, sorted_id, ref_of);
        gather_scatter<<<(total + 15) / 16, 256, 0, stream>>>(raw, sorted_id, ref_of,
                                                              rdist, flag, total,
                                                              /*table_by_flag=*/1);
        mean_seq<<<(B1 + 3) / 4, 256, 0, stream>>>(rdist, comb, flag, B1,
                                                   /*table_by_flag=*/1);
    } else {
        // Fallback: direct wave-per-node gather (R3 path).
        gather_agg<<<B1 / 4, 256, 0, stream>>>(raw, nodes1, neigh1, comb, flag,
                                               /*table_by_flag=*/1);
    }
    gemm_combined<<<B1 / NB, 256, 0, stream>>>(comb, W1, h1, flag, /*out_by_flag=*/0);
    // Layer 2: fused gather+GEMM from bf16 h1 (cache-resident) -> final output.
    sage_layer<<<B2 / NB, 256, 0, stream>>>(h1, W2, nodes2, neigh2, d_out, flag,
                                            /*table_by_flag=*/0, /*out_by_flag=*/1);
}

// Round 7
// 749.137 us; speedup vs baseline: 1.0007x; 1.0007x over previous
//
#include <hip/hip_runtime.h>

// GraphSage 2-layer forward, MI355X (gfx950).
// Inputs: raw[1e6][128], W1[128][256], W2[128][256] (bf16 OR f32 — detected on
// device), nodes1[40960] i32, neigh1[40960][10] i32, nodes2[4096] i32,
// neigh2[4096][10] i32.  out: h2[4096][128] (dtype follows inputs).
// ws: [0..3] flag, [256..] h1[40960][128] bf16, then tbl[1e6][128] bf16 (256MB).
//
// R6 post-mortem: random-pass cost is TRANSACTION-count-bound (~12G lines/s),
// direction-agnostic (R5 read-inversion == R6 write-inversion == 749 us).
// R7: abandon sort/inversion. Revert to R1 fused structure (best, 623 us) and
// halve the random line count: convert the f32 table to bf16 once (sequential,
// ~125 us), gather layer-1 from the bf16 table (4 lines/row instead of 8;
// 256 MB also ~fits L3 for partial hit bonus).

typedef __attribute__((ext_vector_type(8))) short  short8;   // 8 bf16 = 16 B
typedef __attribute__((ext_vector_type(8))) __bf16 bf16x8;   // MFMA operand type
typedef __attribute__((ext_vector_type(4))) float  f32x4;

#define K_NEIGH 10
#define NB      32          // nodes per block
#define PITCH   264         // shorts per LDS combined row (256 + 8 pad)
#define NROW    1000000L    // raw table rows (fixed by problem spec)

__device__ inline float b2f(short s) {
    union { unsigned int u; float f; } c;
    c.u = ((unsigned int)(unsigned short)s) << 16;
    return c.f;
}
__device__ inline short f2b(float f) {
    union { float f; unsigned int u; } c; c.f = f;
    unsigned int u = c.u;
    return (short)((u + 0x7fffu + ((u >> 16) & 1u)) >> 16);  // RNE
}
__device__ inline bf16x8 as_bf16x8(short8 s) {
    union { short8 s; bf16x8 b; } c; c.s = s; return c.b;
}

// f32-vs-bf16 input detection (see R0 notes). 1 wave, ballot.
__global__ void detect_f32(const unsigned short* __restrict__ w, int* __restrict__ flag) {
    const int lane = threadIdx.x;                     // 64 threads, 1 wave
    unsigned int e = ((unsigned int)w[2 * lane] >> 7) & 0xFFu;  // bf16 exp field
    unsigned long long m = __ballot(e >= 132u);                 // |x| >= 32
    if (lane == 0) *flag = (m != 0ull) ? 1 : 0;
}

// ---------------------------------------------------------------------------
// Convert raw table to a dense bf16 table in ws (sequential, BW-bound).
// flag=1: f32 -> bf16 (RNE, identical rounding to the gather's old f2b path).
// flag=0: inputs already bf16 -> plain copy (so layer 1 can always read tbl).
__launch_bounds__(256, 8)
__global__ void conv_bf16(const void* __restrict__ src,
                          short*      __restrict__ dst,
                          const int*  __restrict__ flag,
                          const long n8)              // number of 8-elem groups
{
    long i = (long)blockIdx.x * blockDim.x + threadIdx.x;
    const long stride = (long)gridDim.x * blockDim.x;
    if (*flag) {
        const float* s = (const float*)src;
        for (; i < n8; i += stride) {
            f32x4 a = *(const f32x4*)(s + i * 8);
            f32x4 b = *(const f32x4*)(s + i * 8 + 4);
            short8 o;
#pragma unroll
            for (int j = 0; j < 4; ++j) { o[j] = f2b(a[j]); o[4 + j] = f2b(b[j]); }
            *(short8*)(dst + i * 8) = o;
        }
    } else {
        const short* s = (const short*)src;
        for (; i < n8; i += stride)
            *(short8*)(dst + i * 8) = *(const short8*)(s + i * 8);
    }
}

// ---------------------------------------------------------------------------
// Fused gather + mean + GEMM (R1 structure, verbatim).
// out[i][o] = relu( sum_j concat(table[nodes[i]], mean_k table[neigh[i][k]])[j] * W[o][j] )
// table_by_flag: table dtype follows *flag (1) or is always bf16 (0).
// out_by_flag:   out dtype follows *flag (layer 2) or is always bf16 (layer 1).
__launch_bounds__(256, 2)
__global__ void sage_layer(const void* __restrict__ table,
                           const void* __restrict__ Wv,       // [128][256] row-major
                           const int*  __restrict__ nodes,
                           const int*  __restrict__ neigh,    // [nn][10]
                           void*       __restrict__ outv,     // [nn][128]
                           const int*  __restrict__ flag,
                           const int table_by_flag, const int out_by_flag)
{
    __shared__ __align__(16) short lds[NB * PITCH];
    const int t    = threadIdx.x;
    const int blk  = blockIdx.x;
    const int lane = t & 63;
    const int wave = t >> 6;          // wave w owns out cols [32w, 32w+32)
    const int n15  = lane & 15;
    const int q    = lane >> 4;
    const int f32in = *flag;                       // wave-uniform
    const bool t32 = table_by_flag && f32in;
    const bool o32 = out_by_flag && f32in;

    // ---- B fragments in registers: B[k][n] = W[n][k]; W rows are k-contiguous.
    short8 bfrag[2][8];
    if (!f32in) {
        const short* W = (const short*)Wv;
#pragma unroll
        for (int ot = 0; ot < 2; ++ot) {
            const int o = wave * 32 + ot * 16 + n15;
#pragma unroll
            for (int fk = 0; fk < 8; ++fk)
                bfrag[ot][fk] = *(const short8*)(W + o * 256 + fk * 32 + q * 8);
        }
    } else {
        const float* W = (const float*)Wv;
#pragma unroll
        for (int ot = 0; ot < 2; ++ot) {
            const int o = wave * 32 + ot * 16 + n15;
#pragma unroll
            for (int fk = 0; fk < 8; ++fk) {
                const float* p = W + o * 256 + fk * 32 + q * 8;
                f32x4 v0 = *(const f32x4*)p;
                f32x4 v1 = *(const f32x4*)(p + 4);
                short8 s;
#pragma unroll
                for (int i = 0; i < 4; ++i) { s[i] = f2b(v0[i]); s[4 + i] = f2b(v1[i]); }
                bfrag[ot][fk] = s;
            }
        }
    }

    // ---- Stage combined[NB][256] bf16 into LDS: 8 threads/node, 16 dims each.
    {
        const int m    = t >> 3;       // node slot 0..31
        const int part = t & 7;        // dims [part*16, part*16+16)
        const int gi   = blk * NB + m;
        const int self_id = nodes[gi];
        short8 s0, s1;
        float a[16];
#pragma unroll
        for (int i = 0; i < 16; ++i) a[i] = 0.f;

        if (!t32) {
            const short* srow = (const short*)table + (long)self_id * 128 + part * 16;
            s0 = *(const short8*)(srow);
            s1 = *(const short8*)(srow + 8);
            for (int k = 0; k < K_NEIGH; ++k) {
                const int nid = neigh[gi * K_NEIGH + k];
                const short* nrow = (const short*)table + (long)nid * 128 + part * 16;
                short8 v0 = *(const short8*)(nrow);
                short8 v1 = *(const short8*)(nrow + 8);
#pragma unroll
                for (int i = 0; i < 8; ++i) { a[i] += b2f(v0[i]); a[8 + i] += b2f(v1[i]); }
            }
        } else {
            const float* srow = (const float*)table + (long)self_id * 128 + part * 16;
            f32x4 u0 = *(const f32x4*)(srow);
            f32x4 u1 = *(const f32x4*)(srow + 4);
            f32x4 u2 = *(const f32x4*)(srow + 8);
            f32x4 u3 = *(const f32x4*)(srow + 12);
#pragma unroll
            for (int i = 0; i < 4; ++i) {
                s0[i] = f2b(u0[i]); s0[4 + i] = f2b(u1[i]);
                s1[i] = f2b(u2[i]); s1[4 + i] = f2b(u3[i]);
            }
            for (int k = 0; k < K_NEIGH; ++k) {
                const int nid = neigh[gi * K_NEIGH + k];
                const float* nrow = (const float*)table + (long)nid * 128 + part * 16;
                f32x4 v0 = *(const f32x4*)(nrow);
                f32x4 v1 = *(const f32x4*)(nrow + 4);
                f32x4 v2 = *(const f32x4*)(nrow + 8);
                f32x4 v3 = *(const f32x4*)(nrow + 12);
#pragma unroll
                for (int i = 0; i < 4; ++i) {
                    a[i] += v0[i]; a[4 + i] += v1[i]; a[8 + i] += v2[i]; a[12 + i] += v3[i];
                }
            }
        }
        short8 g0, g1;
#pragma unroll
        for (int i = 0; i < 8; ++i) { g0[i] = f2b(a[i] * 0.1f); g1[i] = f2b(a[8 + i] * 0.1f); }
        short* dst = lds + m * PITCH + part * 16;
        *(short8*)(dst)       = s0;   // self -> cols [0,128)
        *(short8*)(dst + 8)   = s1;
        *(short8*)(dst + 128) = g0;   // agg  -> cols [128,256)
        *(short8*)(dst + 136) = g1;
    }
    __syncthreads();

    // ---- MFMA: [32 nodes] x [this wave's 32 outs], K=256.
    f32x4 acc[2][2] = {};
#pragma unroll
    for (int mb = 0; mb < 2; ++mb) {
        const short* arow = lds + (mb * 16 + n15) * PITCH + q * 8;
        short8 af[8];
#pragma unroll
        for (int fk = 0; fk < 8; ++fk) af[fk] = *(const short8*)(arow + fk * 32);
#pragma unroll
        for (int ot = 0; ot < 2; ++ot)
#pragma unroll
            for (int fk = 0; fk < 8; ++fk)
                acc[mb][ot] = __builtin_amdgcn_mfma_f32_16x16x32_bf16(
                    as_bf16x8(af[fk]), as_bf16x8(bfrag[ot][fk]), acc[mb][ot], 0, 0, 0);
    }

    // ---- Epilogue: ReLU + store. D layout: col = lane&15, row = (lane>>4)*4 + r.
#pragma unroll
    for (int mb = 0; mb < 2; ++mb)
#pragma unroll
        for (int ot = 0; ot < 2; ++ot) {
            const int col = wave * 32 + ot * 16 + n15;
#pragma unroll
            for (int r = 0; r < 4; ++r) {
                const long row = blk * NB + mb * 16 + q * 4 + r;
                float v = acc[mb][ot][r];
                v = v > 0.f ? v : 0.f;
                if (!o32) ((short*)outv)[row * 128 + col] = f2b(v);
                else      ((float*)outv)[row * 128 + col] = v;
            }
        }
}

extern "C" void kernel_launch(void* const* d_in, const int* in_sizes, int n_in,
                              void* d_out, int out_size, void* d_ws, size_t ws_size,
                              hipStream_t stream) {
    const void* raw    = d_in[0];
    const void* W1     = d_in[1];
    const void* W2     = d_in[2];
    const int*  nodes1 = (const int*)d_in[3];
    const int*  neigh1 = (const int*)d_in[4];
    const int*  nodes2 = (const int*)d_in[5];
    const int*  neigh2 = (const int*)d_in[6];

    const int B1 = in_sizes[3];                   // 40960
    const int B2 = in_sizes[5];                   // 4096

    char*  ws    = (char*)d_ws;
    int*   flag  = (int*)ws;
    short* h1    = (short*)(ws + 256);                          // [B1][128] bf16
    size_t o_tbl = 256 + (size_t)B1 * 128 * 2;
    short* tbl   = (short*)(ws + o_tbl);                        // [NROW][128] bf16
    size_t need  = o_tbl + (size_t)NROW * 128 * 2;              // ~267 MB

    detect_f32<<<1, 64, 0, stream>>>((const unsigned short*)W1, flag);

    if (ws_size >= need) {
        // Sequential f32->bf16 table conversion (halves random line count).
        const long n8 = NROW * 128 / 8;                         // 16M groups
        conv_bf16<<<8192, 256, 0, stream>>>(raw, tbl, flag, n8);
        // Layer 1: fused gather+mean+GEMM from the bf16 table.
        sage_layer<<<B1 / NB, 256, 0, stream>>>(tbl, W1, nodes1, neigh1, h1, flag,
                                                /*table_by_flag=*/0, /*out_by_flag=*/0);
    } else {
        // Fallback (R1 exact): gather straight from the f32 table.
        sage_layer<<<B1 / NB, 256, 0, stream>>>(raw, W1, nodes1, neigh1, h1, flag,
                                                /*table_by_flag=*/1, /*out_by_flag=*/0);
    }
    // Layer 2: fused gather+GEMM from bf16 h1 (cache-resident) -> final output.
    sage_layer<<<B2 / NB, 256, 0, stream>>>(h1, W2, nodes2, neigh2, d_out, flag,
                                            /*table_by_flag=*/0, /*out_by_flag=*/1);
}